// Round 1
// baseline (1656.338 us; speedup 1.0000x reference)
//
#include <hip/hip_runtime.h>

#define BLOCK 256
#define NPB 64          // nodes per block (one per lane; 4 waves split columns)
#define NF 8            // node features
#define NE 32           // embed dim
#define NI 40           // F + E
#define NH 64           // hidden
#define LDSW 68         // LDS row stride in floats: 17 x float4 (odd 16B stride -> conflict-free b128)

typedef float fvec16 __attribute__((ext_vector_type(16)));
typedef float fvec8  __attribute__((ext_vector_type(8)));

// Pre-pass: per main-kernel block, binary-search the segment containing its first node.
__global__ void seg_starts(const int* __restrict__ ptr, int* __restrict__ blockseg,
                           int nb, int n, int m)
{
    int b = blockIdx.x * blockDim.x + threadIdx.x;
    if (b >= nb) return;
    long long n0 = (long long)b * NPB;
    int node0 = (int)(n0 < n ? n0 : (long long)(n - 1));
    int lo = 0, hi = m;
    while (hi - lo > 1) {
        int mid = (lo + hi) >> 1;
        if (ptr[mid] <= node0) lo = mid; else hi = mid;
    }
    blockseg[b] = lo;
}

template<bool PRESEG>
__global__ __launch_bounds__(BLOCK, 4) void dag_mlp_seg(
    const float* __restrict__ x, const float* __restrict__ h_node,
    const float* __restrict__ W1, const float* __restrict__ b1,
    const float* __restrict__ W2, const float* __restrict__ b2,
    const float* __restrict__ W3, const float* __restrict__ b3,
    const int* __restrict__ ptr, float* __restrict__ out,
    const int* __restrict__ blockseg, int n, int m)
{
    // Single LDS buffer: cross-wave activation handoff only. 64 rows x 68 floats = 17.4 KB.
    __shared__ float sH[NPB * LDSW];

    const int tid = threadIdx.x;
    const int nd  = tid & 63;                                   // node-in-block = lane
    const int g   = __builtin_amdgcn_readfirstlane(tid >> 6);   // wave = column group
    const long long node0 = (long long)blockIdx.x * NPB;
    const long long node  = node0 + nd;
    const bool valid = node < n;
    const int nodeC = (int)(valid ? node : (long long)(n - 1)); // clamped (outputs guarded)

    // ---- load this lane's input row [x(8) | h_node(32)] straight into VGPRs ----
    float in[NI];
    {
        const float4* xr = reinterpret_cast<const float4*>(x) + (size_t)nodeC * (NF / 4);
#pragma unroll
        for (int i = 0; i < NF / 4; ++i) {
            float4 v = xr[i];
            in[i*4+0] = v.x; in[i*4+1] = v.y; in[i*4+2] = v.z; in[i*4+3] = v.w;
        }
        const float4* hr = reinterpret_cast<const float4*>(h_node) + (size_t)nodeC * (NE / 4);
#pragma unroll
        for (int i = 0; i < NE / 4; ++i) {
            float4 v = hr[i];
            in[NF+i*4+0] = v.x; in[NF+i*4+1] = v.y; in[NF+i*4+2] = v.z; in[NF+i*4+3] = v.w;
        }
    }

    float acc[16];

    // ---- layer 1: [40] -> [64], wave g computes cols g*16..g*16+15; pure s_load + FMA ----
    {
        fvec16 bv = *reinterpret_cast<const fvec16*>(b1 + g * 16);
#pragma unroll
        for (int c = 0; c < 16; ++c) acc[c] = bv[c];
#pragma unroll
        for (int k = 0; k < NI; ++k) {
            fvec16 w = *reinterpret_cast<const fvec16*>(W1 + k * NH + g * 16);
            const float s = in[k];
#pragma unroll
            for (int c = 0; c < 16; ++c) acc[c] = fmaf(s, w[c], acc[c]);
        }
        float* o = &sH[nd * LDSW + g * 16];
#pragma unroll
        for (int i = 0; i < 4; ++i) {
            float4 v = { fmaxf(acc[i*4+0], 0.f), fmaxf(acc[i*4+1], 0.f),
                         fmaxf(acc[i*4+2], 0.f), fmaxf(acc[i*4+3], 0.f) };
            *reinterpret_cast<float4*>(o + i*4) = v;
        }
    }
    __syncthreads();

    // ---- gather full H1 row into VGPRs (16x ds_read_b128, conflict-free) ----
    float h1[NH];
#pragma unroll
    for (int i = 0; i < NH / 4; ++i) {
        float4 v = *reinterpret_cast<const float4*>(&sH[nd * LDSW + i*4]);
        h1[i*4+0] = v.x; h1[i*4+1] = v.y; h1[i*4+2] = v.z; h1[i*4+3] = v.w;
    }
    __syncthreads();    // all reads done before rows are overwritten with H2

    // ---- layer 2: [64] -> [64] ----
    {
        fvec16 bv = *reinterpret_cast<const fvec16*>(b2 + g * 16);
#pragma unroll
        for (int c = 0; c < 16; ++c) acc[c] = bv[c];
#pragma unroll
        for (int k = 0; k < NH; ++k) {
            fvec16 w = *reinterpret_cast<const fvec16*>(W2 + k * NH + g * 16);
            const float s = h1[k];
#pragma unroll
            for (int c = 0; c < 16; ++c) acc[c] = fmaf(s, w[c], acc[c]);
        }
        float* o = &sH[nd * LDSW + g * 16];
#pragma unroll
        for (int i = 0; i < 4; ++i) {
            float4 v = { fmaxf(acc[i*4+0], 0.f), fmaxf(acc[i*4+1], 0.f),
                         fmaxf(acc[i*4+2], 0.f), fmaxf(acc[i*4+3], 0.f) };
            *reinterpret_cast<float4*>(o + i*4) = v;
        }
    }
    __syncthreads();

    // ---- gather full H2 row (last LDS use; no further barrier needed) ----
    float h2[NH];
#pragma unroll
    for (int i = 0; i < NH / 4; ++i) {
        float4 v = *reinterpret_cast<const float4*>(&sH[nd * LDSW + i*4]);
        h2[i*4+0] = v.x; h2[i*4+1] = v.y; h2[i*4+2] = v.z; h2[i*4+3] = v.w;
    }

    // ---- layer 3: [64] -> [32], wave g computes cols g*8..g*8+7 ----
    float ov[8];
    {
        fvec8 bv = *reinterpret_cast<const fvec8*>(b3 + g * 8);
#pragma unroll
        for (int c = 0; c < 8; ++c) ov[c] = bv[c];
#pragma unroll
        for (int k = 0; k < NH; ++k) {
            fvec8 w = *reinterpret_cast<const fvec8*>(W3 + k * NE + g * 8);
            const float s = h2[k];
#pragma unroll
            for (int c = 0; c < 8; ++c) ov[c] = fmaf(s, w[c], ov[c]);
        }
    }

    // ---- segment id: block-level start (precomputed or uniform search) + short per-lane scan ----
    int seg;
    if constexpr (PRESEG) {
        seg = blockseg[blockIdx.x];
    } else {
        const int node0C = (int)(node0 < n ? node0 : (long long)(n - 1));
        int lo = 0, hi = m;
        while (hi - lo > 1) {                 // wave-uniform: single scalar-load chain
            int mid = (lo + hi) >> 1;
            if (ptr[mid] <= node0C) lo = mid; else hi = mid;
        }
        seg = lo;
    }
    // advance to largest seg with ptr[seg] <= nodeC (avg <1 trip; ptr line is L1-hot)
    while (seg + 1 < m && ptr[seg + 1] <= nodeC) ++seg;

    // ---- wave-level segmented suffix reduction; lanes = consecutive nodes ----
    const int lane = nd;
    const int segUp = __shfl_up(seg, 1);
    const bool head = (lane == 0) || (segUp != seg);

    bool take[6];
#pragma unroll
    for (int i = 0; i < 6; ++i) {
        const int d = 1 << i;
        const int s2 = __shfl_down(seg, d);
        take[i] = (lane + d < 64) && (s2 == seg);
    }

#pragma unroll
    for (int j = 0; j < 8; ++j) {
        float v = valid ? ov[j] : 0.f;
#pragma unroll
        for (int i = 0; i < 6; ++i) {
            const float w = __shfl_down(v, 1 << i);
            if (take[i]) v += w;
        }
        if (head && valid) {
            atomicAdd(&out[(size_t)seg * NE + g * 8 + j], v);
        }
    }
}

extern "C" void kernel_launch(void* const* d_in, const int* in_sizes, int n_in,
                              void* d_out, int out_size, void* d_ws, size_t ws_size,
                              hipStream_t stream) {
    const float* x      = (const float*)d_in[0];
    const float* h_node = (const float*)d_in[1];
    const float* W1     = (const float*)d_in[2];
    const float* b1     = (const float*)d_in[3];
    const float* W2     = (const float*)d_in[4];
    const float* b2     = (const float*)d_in[5];
    const float* W3     = (const float*)d_in[6];
    const float* b3     = (const float*)d_in[7];
    const int*   ptr    = (const int*)d_in[8];
    float* out = (float*)d_out;

    const int n = in_sizes[0] / NF;   // 2,000,000 nodes
    const int m = out_size / NE;      // 20,000 segments

    // out is accumulated with atomics; harness poisons it with 0xAA.
    hipMemsetAsync(d_out, 0, (size_t)out_size * sizeof(float), stream);

    const int nb = (n + NPB - 1) / NPB;
    const bool preseg = (d_ws != nullptr) && (ws_size >= (size_t)nb * sizeof(int));

    if (preseg) {
        int* blockseg = (int*)d_ws;
        seg_starts<<<(nb + 255) / 256, 256, 0, stream>>>(ptr, blockseg, nb, n, m);
        dag_mlp_seg<true><<<nb, BLOCK, 0, stream>>>(x, h_node, W1, b1, W2, b2, W3, b3,
                                                    ptr, out, blockseg, n, m);
    } else {
        dag_mlp_seg<false><<<nb, BLOCK, 0, stream>>>(x, h_node, W1, b1, W2, b2, W3, b3,
                                                     ptr, out, nullptr, n, m);
    }
}